// Round 6
// baseline (378.076 us; speedup 1.0000x reference)
//
#include <hip/hip_runtime.h>

typedef __bf16 bf16_t;
typedef __bf16 bf16x8 __attribute__((ext_vector_type(8)));
typedef float f32x4 __attribute__((ext_vector_type(4)));
typedef unsigned short ushort_t;

#define MFMA_16x16x32(a, b, c) __builtin_amdgcn_mfma_f32_16x16x32_bf16((a), (b), (c), 0, 0, 0)

// async global->LDS, 16B per lane. LDS dest must be wave-uniform; HW adds lane*16.
__device__ __forceinline__ void async_ld16(const void* gptr, void* lptr) {
  typedef __attribute__((address_space(1))) const unsigned int as1_t;
  typedef __attribute__((address_space(3))) unsigned int as3_t;
  __builtin_amdgcn_global_load_lds((as1_t*)(unsigned long long)gptr,
                                   (as3_t*)(unsigned int)(unsigned long long)lptr,
                                   16, 0, 0);
}

// ---------------------------------------------------------------------------
// Input-dtype detector (f32-read-as-bf16 has ~47% wild exponents in low halves).
// ---------------------------------------------------------------------------
__global__ void detect_dtype(const ushort_t* __restrict__ x, int* __restrict__ flag) {
  __shared__ int cnt[256];
  int c = 0;
#pragma unroll
  for (int i = 0; i < 16; ++i) {
    const ushort_t u = x[threadIdx.x * 16 + i];
    const int e = (u >> 7) & 0xFF;
    if ((u & 0x7FFF) != 0 && (e < 0x3A || e > 0xC0)) ++c;
  }
  cnt[threadIdx.x] = c;
  __syncthreads();
  if (threadIdx.x == 0) {
    int t = 0;
    for (int i = 0; i < 256; ++i) t += cnt[i];
    *flag = (t > 512) ? 1 : 0;
  }
}

// ---------------------------------------------------------------------------
// Normalize input to bf16 (flag==1: f32 src; else 16B copy). n8 = elems/8.
// ---------------------------------------------------------------------------
__global__ __launch_bounds__(256) void convert_to_bf16(const void* __restrict__ src,
                                                       bf16_t* __restrict__ dst, int n8,
                                                       const int* __restrict__ flag) {
  const int isF32 = *flag;
  int i = blockIdx.x * 256 + threadIdx.x;
  const int stride = gridDim.x * 256;
  if (isF32) {
    const float4* s = (const float4*)src;
    for (; i < n8; i += stride) {
      const float4 a = s[(size_t)i * 2];
      const float4 b = s[(size_t)i * 2 + 1];
      bf16x8 o;
      o[0] = (bf16_t)a.x; o[1] = (bf16_t)a.y; o[2] = (bf16_t)a.z; o[3] = (bf16_t)a.w;
      o[4] = (bf16_t)b.x; o[5] = (bf16_t)b.y; o[6] = (bf16_t)b.z; o[7] = (bf16_t)b.w;
      *(bf16x8*)(dst + (size_t)i * 8) = o;
    }
  } else {
    const uint4* s = (const uint4*)src;
    for (; i < n8; i += stride) ((uint4*)dst)[i] = s[i];
  }
}

// ---------------------------------------------------------------------------
// Fused convert + 64x64 transpose for weights: in (f32 or bf16 per flag)
// [R][C] -> out bf16 [C][R].
// ---------------------------------------------------------------------------
__global__ __launch_bounds__(256) void transpose_cvt(const void* __restrict__ in,
                                                     ushort_t* __restrict__ out,
                                                     int R, int C,
                                                     const int* __restrict__ flag) {
  __shared__ alignas(16) ushort_t t[64 * 72];
  const int tid = threadIdx.x;
  const int c0 = blockIdx.x * 64;
  const int r0 = blockIdx.y * 64;
  if (*flag) {
    const float* s = (const float*)in;
#pragma unroll
    for (int it = 0; it < 4; ++it) {
      int cid = tid + it * 256;            // 0..1023
      int row = cid >> 4, ch = (cid & 15) * 4;  // 4 f32 per chunk
      const float4 v = *(const float4*)(s + (size_t)(r0 + row) * C + c0 + ch);
      ushort_t* tp = t + row * 72 + ch;
      tp[0] = (ushort_t)__builtin_bit_cast(unsigned short, (bf16_t)v.x);
      tp[1] = (ushort_t)__builtin_bit_cast(unsigned short, (bf16_t)v.y);
      tp[2] = (ushort_t)__builtin_bit_cast(unsigned short, (bf16_t)v.z);
      tp[3] = (ushort_t)__builtin_bit_cast(unsigned short, (bf16_t)v.w);
    }
  } else {
    const ushort_t* s = (const ushort_t*)in;
#pragma unroll
    for (int it = 0; it < 2; ++it) {
      int cid = tid + it * 256;
      int row = cid >> 3, co = (cid & 7) * 8;
      *(uint4*)(t + row * 72 + co) = *(const uint4*)(s + (size_t)(r0 + row) * C + c0 + co);
    }
  }
  __syncthreads();
#pragma unroll
  for (int it = 0; it < 2; ++it) {
    int cid = tid + it * 256;
    int orow = cid >> 3, ko = (cid & 7) * 8;
    uint4 u;
    ushort_t* tp = (ushort_t*)&u;
#pragma unroll
    for (int j = 0; j < 8; ++j) tp[j] = t[(ko + j) * 72 + orow];
    *(uint4*)(out + (size_t)(c0 + orow) * R + r0 + ko) = u;
  }
}

// ---------------------------------------------------------------------------
// Batched V transpose: qkv[b*4096+l][2048+h*64+d] -> vT[((b*16+h)*64+d)*4096+l]
// grid (64 l-tiles, 64 bh). Fully coalesced 16B both sides.
// ---------------------------------------------------------------------------
__global__ __launch_bounds__(256) void transpose_v(const ushort_t* __restrict__ qkv,
                                                   ushort_t* __restrict__ vT) {
  __shared__ alignas(16) ushort_t t[64 * 72];
  const int tid = threadIdx.x;
  const int l0 = blockIdx.x * 64;
  const int bh = blockIdx.y;
  const int b = bh >> 4, h = bh & 15;
  const ushort_t* src = qkv + ((size_t)(b * 4096 + l0)) * 3072 + 2048 + h * 64;
#pragma unroll
  for (int it = 0; it < 2; ++it) {
    int cid = tid + it * 256;
    int row = cid >> 3, co = (cid & 7) * 8;
    *(uint4*)(t + row * 72 + co) = *(const uint4*)(src + (size_t)row * 3072 + co);
  }
  __syncthreads();
  ushort_t* dst = vT + ((size_t)bh * 64) * 4096 + l0;
#pragma unroll
  for (int it = 0; it < 2; ++it) {
    int cid = tid + it * 256;
    int d = cid >> 3, ko = (cid & 7) * 8;
    uint4 u;
    ushort_t* tp = (ushort_t*)&u;
#pragma unroll
    for (int j = 0; j < 8; ++j) tp[j] = t[(ko + j) * 72 + d];
    *(uint4*)(dst + (size_t)d * 4096 + ko) = u;
  }
}

// ---------------------------------------------------------------------------
// QKV GEMM: C[M][N] = A[M][K] * Bt[N][K]^T.  256x256 tile, BK=32, 8 waves,
// 512 threads, TRIPLE-buffered LDS, 1 barrier + counted vmcnt(4) per K-tile.
// Measured stable 110.5 us at M=16384,N=3072,K=1024.
// ---------------------------------------------------------------------------
__global__ __launch_bounds__(512) void gemm_bf16(const bf16_t* __restrict__ A, int lda,
                                                 const bf16_t* __restrict__ Bt,
                                                 void* __restrict__ Cout, int N_out,
                                                 int K, const int* __restrict__ flag) {
  __shared__ alignas(16) bf16_t smem[49152];  // 96 KiB: 3 x [A 8K | B 8K] elems
  const int tid = threadIdx.x;
  const int wave = tid >> 6;
  const int lane = tid & 63;
  const int l15 = lane & 15;
  const int quad = lane >> 4;
  const int wm = wave >> 2;  // 0..1
  const int wn = wave & 3;   // 0..3

  int lin = blockIdx.y * gridDim.x + blockIdx.x;
  const int nwg = gridDim.x * gridDim.y;
  if ((nwg & 7) == 0) lin = (lin & 7) * (nwg >> 3) + (lin >> 3);
  const int tn = (lin % gridDim.x) * 256;
  const int tm = (lin / gridDim.x) * 256;

  f32x4 acc[8][4];
#pragma unroll
  for (int i = 0; i < 8; ++i)
#pragma unroll
    for (int j = 0; j < 4; ++j) acc[i][j] = (f32x4){0.f, 0.f, 0.f, 0.f};

  const int r_st = tid >> 2;
  const int csrc = ((tid & 3) ^ ((tid >> 3) & 3)) * 8;
  const int wofs = wave * 512;

  const int rowA = wm * 16 + l15;
  const int rowB = wn * 16 + l15;
  const int cfr = (quad ^ ((l15 >> 1) & 3)) * 8;

  const int NT = K >> 5;

#define STAGE_HALF(G, ldg, grow0, kk, base)                                  \
  async_ld16((G) + (size_t)((grow0) + r_st) * (ldg) + (kk) + csrc,           \
             &smem[(base) + wofs])

#define STAGE4(kk, base)                                \
  do {                                                  \
    STAGE_HALF(A, lda, tm, (kk), (base));               \
    STAGE_HALF(Bt, K, tn, (kk), (base) + 8192);         \
    STAGE_HALF(Bt, K, tn + 128, (kk), (base) + 12288);  \
    STAGE_HALF(A, lda, tm + 128, (kk), (base) + 4096);  \
  } while (0)

  STAGE4(0, 0);
  STAGE4(32, 16384);
  asm volatile("s_waitcnt vmcnt(4)" ::: "memory");
  __builtin_amdgcn_s_barrier();

  int rb = 0;
  for (int t = 0; t < NT; ++t) {
    const int kst = (t + 2) << 5;
    const bool pf = (kst < K);
    const int sb = (rb >= 16384) ? rb - 16384 : rb + 32768;
    if (pf) STAGE4(kst, sb);

    bf16x8 a_[8], b_[4];
#pragma unroll
    for (int mh = 0; mh < 2; ++mh)
#pragma unroll
      for (int q = 0; q < 4; ++q)
        a_[mh * 4 + q] = *(const bf16x8*)&smem[rb + mh * 4096 +
                                               ((q * 32 + rowA) << 5) + cfr];
#pragma unroll
    for (int nh = 0; nh < 2; ++nh)
#pragma unroll
      for (int jn = 0; jn < 2; ++jn)
        b_[nh * 2 + jn] = *(const bf16x8*)&smem[rb + 8192 + nh * 4096 +
                                                ((jn * 64 + rowB) << 5) + cfr];

    __builtin_amdgcn_s_setprio(1);
#pragma unroll
    for (int f = 0; f < 8; ++f)
#pragma unroll
      for (int n = 0; n < 4; ++n) acc[f][n] = MFMA_16x16x32(a_[f], b_[n], acc[f][n]);
    __builtin_amdgcn_s_setprio(0);

    asm volatile("s_waitcnt vmcnt(4)" ::: "memory");
    if (!pf) asm volatile("s_waitcnt vmcnt(0)" ::: "memory");
    __builtin_amdgcn_s_barrier();
    rb = (rb == 32768) ? 0 : rb + 16384;
  }

  __syncthreads();

  const int isF32 = flag ? *flag : 0;
  if (isF32) {
#pragma unroll
    for (int f = 0; f < 8; ++f) {
      const int m0 = tm + (f >> 2) * 128 + (f & 3) * 32 + wm * 16 + quad * 4;
#pragma unroll
      for (int nidx = 0; nidx < 4; ++nidx) {
        const int col = tn + (nidx >> 1) * 128 + (nidx & 1) * 64 + wn * 16 + l15;
        float* cp = (float*)Cout + (size_t)m0 * N_out + col;
#pragma unroll
        for (int r = 0; r < 4; ++r) cp[(size_t)r * N_out] = acc[f][nidx][r];
      }
    }
  } else {
    bf16_t* stg = smem + wave * 1152;
#pragma unroll
    for (int f = 0; f < 8; ++f) {
#pragma unroll
      for (int nidx = 0; nidx < 4; ++nidx)
#pragma unroll
        for (int r = 0; r < 4; ++r)
          stg[(quad * 4 + r) * 72 + nidx * 16 + l15] = (bf16_t)acc[f][nidx][r];
      __asm__ volatile("s_waitcnt lgkmcnt(0)" ::: "memory");
      const int m0 = tm + (f >> 2) * 128 + (f & 3) * 32 + wm * 16;
#pragma unroll
      for (int p = 0; p < 2; ++p) {
        const int idx = lane + p * 64;
        const int row = idx >> 3, c8 = (idx & 7) * 8;
        uint4 u = *(const uint4*)(stg + row * 72 + c8);
        const int col = tn + ((c8 >> 5) << 7) + (((c8 >> 4) & 1) << 6) + wn * 16 + (c8 & 15);
        *(uint4*)((bf16_t*)Cout + (size_t)(m0 + row) * N_out + col) = u;
      }
      __asm__ volatile("s_waitcnt lgkmcnt(0)" ::: "memory");
    }
  }
#undef STAGE_HALF
#undef STAGE4
}

// ---------------------------------------------------------------------------
// Out-projection GEMM (separate name for profiler disambiguation).
// 128x128 tile, 4 waves (2x2 of 64x64), 256 threads, SAME 3-buffer BK=32
// schedule + swizzle + vmcnt(4) ledger as gemm_bf16.  Resource math:
// acc 64 VGPR + ~100 arch -> ~164 => 3 waves/SIMD; LDS 48 KB x 3 blocks
// = 144 <= 160 KB => 3 co-resident blocks/CU (vs 1 for the 256 tile at this
// shape), grid (8,128) = 1024 blocks = 4 rounds -> inter-block latency hiding.
// ---------------------------------------------------------------------------
__global__ __launch_bounds__(256, 3) void gemm_out_bf16(const bf16_t* __restrict__ A,
                                                        int lda,
                                                        const bf16_t* __restrict__ Bt,
                                                        void* __restrict__ Cout,
                                                        int N_out, int K,
                                                        const int* __restrict__ flag) {
  __shared__ alignas(16) bf16_t smem[24576];  // 48 KiB: 3 x [A 4K | B 4K] elems
  const int tid = threadIdx.x;
  const int wave = tid >> 6;
  const int lane = tid & 63;
  const int l15 = lane & 15;
  const int quad = lane >> 4;
  const int wm = (wave >> 1) * 64;
  const int wn = (wave & 1) * 64;

  int lin = blockIdx.y * gridDim.x + blockIdx.x;
  const int nwg = gridDim.x * gridDim.y;
  if ((nwg & 7) == 0) lin = (lin & 7) * (nwg >> 3) + (lin >> 3);
  const int tn = (lin % gridDim.x) * 128;
  const int tm = (lin / gridDim.x) * 128;

  f32x4 acc[4][4];
#pragma unroll
  for (int i = 0; i < 4; ++i)
#pragma unroll
    for (int j = 0; j < 4; ++j) acc[i][j] = (f32x4){0.f, 0.f, 0.f, 0.f};

  // staging: 256 threads cover 64 rows x 4 chunks per call; wave w = rows 16w..
  const int r_st = tid >> 2;                          // 0..63
  const int csrc = ((tid & 3) ^ ((tid >> 3) & 3)) * 8;  // swizzled global chunk
  const int wofs = wave * 512;                        // wave-uniform LDS base

  const int cfr = (quad ^ ((l15 >> 1) & 3)) * 8;      // swizzled read chunk

  const int NT = K >> 5;

#define OSTAGE_HALF(G, ldg, grow0, kk, base)                                 \
  async_ld16((G) + (size_t)((grow0) + r_st) * (ldg) + (kk) + csrc,           \
             &smem[(base) + wofs])

  // buffer layout (elems): A rows 0..63 at +0, 64..127 at +2048,
  //                        B rows 0..63 at +4096, 64..127 at +6144.
#define OSTAGE4(kk, base)                               \
  do {                                                  \
    OSTAGE_HALF(A, lda, tm, (kk), (base));              \
    OSTAGE_HALF(A, lda, tm + 64, (kk), (base) + 2048);  \
    OSTAGE_HALF(Bt, K, tn, (kk), (base) + 4096);        \
    OSTAGE_HALF(Bt, K, tn + 64, (kk), (base) + 6144);   \
  } while (0)

  OSTAGE4(0, 0);
  OSTAGE4(32, 8192);
  asm volatile("s_waitcnt vmcnt(4)" ::: "memory");
  __builtin_amdgcn_s_barrier();

  const int aHalf = (wave >> 1) * 2048;  // wm==64 -> rows 64..127 half
  const int bHalf = (wave & 1) * 2048;

  int rb = 0;  // 0, 8192, 16384 cycling
  for (int t = 0; t < NT; ++t) {
    const int kst = (t + 2) << 5;
    const bool pf = (kst < K);
    const int sb = (rb >= 8192) ? rb - 8192 : rb + 16384;
    if (pf) OSTAGE4(kst, sb);

    bf16x8 a_[4], b_[4];
#pragma unroll
    for (int q = 0; q < 4; ++q)
      a_[q] = *(const bf16x8*)&smem[rb + aHalf + ((q * 16 + l15) << 5) + cfr];
#pragma unroll
    for (int j = 0; j < 4; ++j)
      b_[j] = *(const bf16x8*)&smem[rb + 4096 + bHalf + ((j * 16 + l15) << 5) + cfr];

    __builtin_amdgcn_s_setprio(1);
#pragma unroll
    for (int i = 0; i < 4; ++i)
#pragma unroll
      for (int j = 0; j < 4; ++j) acc[i][j] = MFMA_16x16x32(a_[i], b_[j], acc[i][j]);
    __builtin_amdgcn_s_setprio(0);

    asm volatile("s_waitcnt vmcnt(4)" ::: "memory");
    if (!pf) asm volatile("s_waitcnt vmcnt(0)" ::: "memory");
    __builtin_amdgcn_s_barrier();
    rb = (rb == 16384) ? 0 : rb + 8192;
  }

  __syncthreads();

  const int isF32 = flag ? *flag : 0;
  if (isF32) {
#pragma unroll
    for (int i = 0; i < 4; ++i) {
      const int m = tm + wm + i * 16 + quad * 4;
#pragma unroll
      for (int j = 0; j < 4; ++j) {
        const int n = tn + wn + j * 16 + l15;
        float* cp = (float*)Cout + (size_t)m * N_out + n;
#pragma unroll
        for (int r = 0; r < 4; ++r) cp[(size_t)r * N_out] = acc[i][j][r];
      }
    }
  } else {
    bf16_t* stg = smem + wave * 1152;
#pragma unroll
    for (int i = 0; i < 4; ++i) {
#pragma unroll
      for (int j = 0; j < 4; ++j)
#pragma unroll
        for (int r = 0; r < 4; ++r)
          stg[(quad * 4 + r) * 72 + j * 16 + l15] = (bf16_t)acc[i][j][r];
      __asm__ volatile("s_waitcnt lgkmcnt(0)" ::: "memory");
      const int m0 = tm + wm + i * 16;
#pragma unroll
      for (int p = 0; p < 2; ++p) {
        const int idx = lane + p * 64;
        const int row = idx >> 3, c8 = (idx & 7) * 8;
        uint4 u = *(const uint4*)(stg + row * 72 + c8);
        *(uint4*)((bf16_t*)Cout + (size_t)(m0 + row) * N_out + tn + wn + c8) = u;
      }
      __asm__ volatile("s_waitcnt lgkmcnt(0)" ::: "memory");
    }
  }
#undef OSTAGE_HALF
#undef OSTAGE4
}

// ---------------------------------------------------------------------------
// Sliding-window attention. R2 version (best measured) — untouched.
// ---------------------------------------------------------------------------
__global__ __launch_bounds__(256) void attn_swa(bf16_t* qkv, const bf16_t* __restrict__ vT) {
  __shared__ alignas(16) bf16_t k_lds[64 * 72];   // [key][d]
  __shared__ alignas(16) bf16_t vt_lds[64 * 72];  // [d][key]
  __shared__ alignas(16) bf16_t p_lds[4 * 16 * 72];

  int wg = blockIdx.x;
  wg = (wg & 7) * 512 + (wg >> 3);
  const int b = wg >> 10;
  const int h = (wg >> 6) & 15;
  const int qt = wg & 63;
  const int blk = qt >> 2;
  const int wq = qt & 3;
  const int tid = threadIdx.x;
  const int wave = tid >> 6;
  const int lane = tid & 63;
  const int l15 = lane & 15;
  const int quad = lane >> 4;
  const int qw = qt * 64 + wave * 16;

  const size_t qoff = ((size_t)(b * 4096 + qw + l15)) * 3072 + h * 64;
  const bf16x8 qf0 = *(const bf16x8*)(qkv + qoff + quad * 8);
  const bf16x8 qf1 = *(const bf16x8*)(qkv + qoff + 32 + quad * 8);

  f32x4 of[4];
#pragma unroll
  for (int i = 0; i < 4; ++i) of[i] = (f32x4){0.f, 0.f, 0.f, 0.f};
  float m_i[4], l_i[4];
#pragma unroll
  for (int r = 0; r < 4; ++r) {
    m_i[r] = -1e30f;
    l_i[r] = 0.0f;
  }

  const int kb0 = blk * 256 - 256;
  const int kclo = (blk == 0) ? 4 : wq;
  const int kchi = wq + 4;

  const int row0 = tid >> 3;
  const int co8 = (tid & 7) * 8;
  const bf16_t* kbase = qkv + ((size_t)b * 4096) * 3072 + 1024 + h * 64;
  const bf16_t* vbase = vT + (((size_t)b * 16 + h) * 64) * 4096;
  uint4 kr0, kr1, vr0, vr1;

#define ISSUE_KV(KB)                                                           \
  do {                                                                         \
    kr0 = *(const uint4*)(kbase + (size_t)((KB) + row0) * 3072 + co8);         \
    kr1 = *(const uint4*)(kbase + (size_t)((KB) + row0 + 32) * 3072 + co8);    \
    vr0 = *(const uint4*)(vbase + (size_t)row0 * 4096 + (KB) + co8);           \
    vr1 = *(const uint4*)(vbase + (size_t)(row0 + 32) * 4096 + (KB) + co8);    \
  } while (0)

  ISSUE_KV(kb0 + kclo * 64);

  for (int kc = kclo; kc <= kchi; ++kc) {
    const int kb = kb0 + kc * 64;
    __syncthreads();
    *(uint4*)(k_lds + row0 * 72 + co8) = kr0;
    *(uint4*)(k_lds + (row0 + 32) * 72 + co8) = kr1;
    *(uint4*)(vt_lds + row0 * 72 + co8) = vr0;
    *(uint4*)(vt_lds + (row0 + 32) * 72 + co8) = vr1;
    if (kc < kchi) ISSUE_KV(kb + 64);
    __syncthreads();

    f32x4 s[4];
    __builtin_amdgcn_s_setprio(1);
#pragma unroll
    for (int nt = 0; nt < 4; ++nt) {
      bf16x8 kf0 = *(const bf16x8*)(k_lds + (nt * 16 + l15) * 72 + quad * 8);
      bf16x8 kf1 = *(const bf16x8*)(k_lds + (nt * 16 + l15) * 72 + 32 + quad * 8);
      f32x4 z = (f32x4){0.f, 0.f, 0.f, 0.f};
      z = MFMA_16x16x32(qf0, kf0, z);
      z = MFMA_16x16x32(qf1, kf1, z);
      s[nt] = z;
    }
    __builtin_amdgcn_s_setprio(0);

    float sv[4][4];
#pragma unroll
    for (int nt = 0; nt < 4; ++nt) {
      const int key = kb + nt * 16 + l15;
#pragma unroll
      for (int r = 0; r < 4; ++r) {
        const int p = qw + quad * 4 + r;
        const bool valid = (key <= p) && (key + 256 > p);
        sv[nt][r] = valid ? s[nt][r] * 0.125f : -1e30f;
      }
    }
    float rm[4];
#pragma unroll
    for (int r = 0; r < 4; ++r)
      rm[r] = fmaxf(fmaxf(sv[0][r], sv[1][r]), fmaxf(sv[2][r], sv[3][r]));
#pragma unroll
    for (int off = 1; off < 16; off <<= 1)
#pragma unroll
      for (int r = 0; r < 4; ++r) rm[r] = fmaxf(rm[r], __shfl_xor(rm[r], off));

    float mn[4], alpha[4];
#pragma unroll
    for (int r = 0; r < 4; ++r) {
      mn[r] = fmaxf(m_i[r], rm[r]);
      alpha[r] = __expf(m_i[r] - mn[r]);
      m_i[r] = mn[r];
    }

    float rs[4] = {0.f, 0.f, 0.f, 0.f};
#pragma unroll
    for (int nt = 0; nt < 4; ++nt)
#pragma unroll
      for (int r = 0; r < 4; ++r) {
        const float pv = (sv[nt][r] > -1e29f) ? __expf(sv[nt][r] - mn[r]) : 0.0f;
        rs[r] += pv;
        p_lds[wave * 1152 + (quad * 4 + r) * 72 + nt * 16 + l15] = (bf16_t)pv;
      }
#pragma unroll
    for (int off = 1; off < 16; off <<= 1)
#pragma unroll
      for (int r = 0; r < 4; ++r) rs[r] += __shfl_xor(rs[r], off);
#pragma unroll
    for (int r = 0; r < 4; ++r) l_i[r] = l_i[r] * alpha[r] + rs[r];
#pragma unroll
    for (int dt = 0; dt < 4; ++dt)
#pragma unroll
      for (int r = 0; r < 4; ++r) of[dt][r] *= alpha[r];

    __builtin_amdgcn_s_setprio(1);
#pragma unroll
    for (int kk = 0; kk < 2; ++kk) {
      bf16x8 pf = *(const bf16x8*)(p_lds + wave * 1152 + l15 * 72 + kk * 32 + quad * 8);
#pragma unroll
      for (int dt = 0; dt < 4; ++dt) {
        bf16x8 vf = *(const bf16x8*)(vt_lds + (dt * 16 + l15) * 72 + kk * 32 + quad * 8);
        of[dt] = MFMA_16x16x32(pf, vf, of[dt]);
      }
    }
    __builtin_amdgcn_s_setprio(0);
  }
#undef ISSUE_KV

  float inv[4];
#pragma unroll
  for (int r = 0; r < 4; ++r) inv[r] = 1.0f / fmaxf(l_i[r], 1e-20f);
  bf16_t* op = qkv + ((size_t)(b * 4096 + qw)) * 3072 + h * 64;  // overwrite Q cols
#pragma unroll
  for (int dt = 0; dt < 4; ++dt)
#pragma unroll
    for (int r = 0; r < 4; ++r)
      op[(size_t)(quad * 4 + r) * 3072 + dt * 16 + l15] = (bf16_t)(of[dt][r] * inv[r]);
}

// ---------------------------------------------------------------------------
extern "C" void kernel_launch(void* const* d_in, const int* in_sizes, int n_in,
                              void* d_out, int out_size, void* d_ws, size_t ws_size,
                              hipStream_t stream) {
  char* ws = (char*)d_ws;
  bf16_t* wTq = (bf16_t*)(ws);                    // [3072][1024]   6,291,456 B
  bf16_t* wTo = (bf16_t*)(ws + 6291456);          // [1024][1024]   2,097,152 B
  bf16_t* qkv = (bf16_t*)(ws + 8388608);          // [16384][3072] 100,663,296 B
  int* flag = (int*)(ws + 109051904);             // 4 B (total 109,051,908 B)

  bf16_t* xb = (bf16_t*)d_out;   // converted x (32 MB), consumed by QKV GEMM
  bf16_t* vTb = (bf16_t*)d_out;  // then vT (32 MB), consumed by attention,
                                 // then final GEMM writes d_out. Stream-ordered.

  detect_dtype<<<1, 256, 0, stream>>>((const ushort_t*)d_in[0], flag);
  convert_to_bf16<<<1024, 256, 0, stream>>>(d_in[0], xb, 2097152, flag);
  transpose_cvt<<<dim3(48, 16), 256, 0, stream>>>(d_in[1], (ushort_t*)wTq, 1024, 3072,
                                                  flag);
  transpose_cvt<<<dim3(16, 16), 256, 0, stream>>>(d_in[2], (ushort_t*)wTo, 1024, 1024,
                                                  flag);
  gemm_bf16<<<dim3(12, 64), 512, 0, stream>>>(xb, 1024, wTq, qkv, 3072, 1024, nullptr);
  transpose_v<<<dim3(64, 64), 256, 0, stream>>>((const ushort_t*)qkv, (ushort_t*)vTb);
  attn_swa<<<dim3(4096), 256, 0, stream>>>(qkv, vTb);
  gemm_out_bf16<<<dim3(8, 128), 256, 0, stream>>>(qkv, 3072, wTo, d_out, 1024, 1024,
                                                  flag);
}

// Round 7
// 358.559 us; speedup vs baseline: 1.0544x; 1.0544x over previous
//
#include <hip/hip_runtime.h>

typedef __bf16 bf16_t;
typedef __bf16 bf16x8 __attribute__((ext_vector_type(8)));
typedef float f32x4 __attribute__((ext_vector_type(4)));
typedef unsigned short ushort_t;
typedef unsigned short us4 __attribute__((ext_vector_type(4)));

#define MFMA_16x16x32(a, b, c) __builtin_amdgcn_mfma_f32_16x16x32_bf16((a), (b), (c), 0, 0, 0)

// async global->LDS, 16B per lane. LDS dest must be wave-uniform; HW adds lane*16.
__device__ __forceinline__ void async_ld16(const void* gptr, void* lptr) {
  typedef __attribute__((address_space(1))) const unsigned int as1_t;
  typedef __attribute__((address_space(3))) unsigned int as3_t;
  __builtin_amdgcn_global_load_lds((as1_t*)(unsigned long long)gptr,
                                   (as3_t*)(unsigned int)(unsigned long long)lptr,
                                   16, 0, 0);
}

// ---------------------------------------------------------------------------
// Input-dtype detector (f32-read-as-bf16 has ~47% wild exponents in low halves).
// ---------------------------------------------------------------------------
__global__ void detect_dtype(const ushort_t* __restrict__ x, int* __restrict__ flag) {
  __shared__ int cnt[256];
  int c = 0;
#pragma unroll
  for (int i = 0; i < 16; ++i) {
    const ushort_t u = x[threadIdx.x * 16 + i];
    const int e = (u >> 7) & 0xFF;
    if ((u & 0x7FFF) != 0 && (e < 0x3A || e > 0xC0)) ++c;
  }
  cnt[threadIdx.x] = c;
  __syncthreads();
  if (threadIdx.x == 0) {
    int t = 0;
    for (int i = 0; i < 256; ++i) t += cnt[i];
    *flag = (t > 512) ? 1 : 0;
  }
}

// ---------------------------------------------------------------------------
// Normalize input to bf16 (flag==1: f32 src; else 16B copy). n8 = elems/8.
// ---------------------------------------------------------------------------
__global__ __launch_bounds__(256) void convert_to_bf16(const void* __restrict__ src,
                                                       bf16_t* __restrict__ dst, int n8,
                                                       const int* __restrict__ flag) {
  const int isF32 = *flag;
  int i = blockIdx.x * 256 + threadIdx.x;
  const int stride = gridDim.x * 256;
  if (isF32) {
    const float4* s = (const float4*)src;
    for (; i < n8; i += stride) {
      const float4 a = s[(size_t)i * 2];
      const float4 b = s[(size_t)i * 2 + 1];
      bf16x8 o;
      o[0] = (bf16_t)a.x; o[1] = (bf16_t)a.y; o[2] = (bf16_t)a.z; o[3] = (bf16_t)a.w;
      o[4] = (bf16_t)b.x; o[5] = (bf16_t)b.y; o[6] = (bf16_t)b.z; o[7] = (bf16_t)b.w;
      *(bf16x8*)(dst + (size_t)i * 8) = o;
    }
  } else {
    const uint4* s = (const uint4*)src;
    for (; i < n8; i += stride) ((uint4*)dst)[i] = s[i];
  }
}

// ---------------------------------------------------------------------------
// Fused convert + 64x64 transpose for weights: in (f32 or bf16 per flag)
// [R][C] -> out bf16 [C][R].
// ---------------------------------------------------------------------------
__global__ __launch_bounds__(256) void transpose_cvt(const void* __restrict__ in,
                                                     ushort_t* __restrict__ out,
                                                     int R, int C,
                                                     const int* __restrict__ flag) {
  __shared__ alignas(16) ushort_t t[64 * 72];
  const int tid = threadIdx.x;
  const int c0 = blockIdx.x * 64;
  const int r0 = blockIdx.y * 64;
  if (*flag) {
    const float* s = (const float*)in;
#pragma unroll
    for (int it = 0; it < 4; ++it) {
      int cid = tid + it * 256;            // 0..1023
      int row = cid >> 4, ch = (cid & 15) * 4;  // 4 f32 per chunk
      const float4 v = *(const float4*)(s + (size_t)(r0 + row) * C + c0 + ch);
      ushort_t* tp = t + row * 72 + ch;
      tp[0] = (ushort_t)__builtin_bit_cast(unsigned short, (bf16_t)v.x);
      tp[1] = (ushort_t)__builtin_bit_cast(unsigned short, (bf16_t)v.y);
      tp[2] = (ushort_t)__builtin_bit_cast(unsigned short, (bf16_t)v.z);
      tp[3] = (ushort_t)__builtin_bit_cast(unsigned short, (bf16_t)v.w);
    }
  } else {
    const ushort_t* s = (const ushort_t*)in;
#pragma unroll
    for (int it = 0; it < 2; ++it) {
      int cid = tid + it * 256;
      int row = cid >> 3, co = (cid & 7) * 8;
      *(uint4*)(t + row * 72 + co) = *(const uint4*)(s + (size_t)(r0 + row) * C + c0 + co);
    }
  }
  __syncthreads();
#pragma unroll
  for (int it = 0; it < 2; ++it) {
    int cid = tid + it * 256;
    int orow = cid >> 3, ko = (cid & 7) * 8;
    uint4 u;
    ushort_t* tp = (ushort_t*)&u;
#pragma unroll
    for (int j = 0; j < 8; ++j) tp[j] = t[(ko + j) * 72 + orow];
    *(uint4*)(out + (size_t)(c0 + orow) * R + r0 + ko) = u;
  }
}

// ---------------------------------------------------------------------------
// GEMM: C[M][N] = A[M][K] * Bt[N][K]^T.  256x256 tile, BK=32, 8 waves,
// 512 threads, TRIPLE-buffered LDS, 1 barrier + counted vmcnt(4) per K-tile.
// Template TAG gives QKV (0) and out-proj (1) distinct mangled names for
// profiler disambiguation; code is identical.
// V-FUSION: for QKV (vT != nullptr), blocks with tn >= 2048 hold exactly the
// V columns; each lane's acc fragment has 4 CONSECUTIVE rows (pos = quad*4+r)
// for a fixed col -> store packed bf16x4 (8B) straight to the transposed
// vT[(b*1024 + c-2048)*4096 + pos] layout.  No LDS shuffle, no transpose_v
// kernel, and the V columns are never written to qkv (-32 MB writes).
// ---------------------------------------------------------------------------
template <int TAG>
__global__ __launch_bounds__(512) void gemm_bf16_t(const bf16_t* __restrict__ A, int lda,
                                                   const bf16_t* __restrict__ Bt,
                                                   void* __restrict__ Cout, int N_out,
                                                   int K, const int* __restrict__ flag,
                                                   bf16_t* __restrict__ vT) {
  __shared__ alignas(16) bf16_t smem[49152];  // 96 KiB: 3 x [A 8K | B 8K] elems
  const int tid = threadIdx.x;
  const int wave = tid >> 6;
  const int lane = tid & 63;
  const int l15 = lane & 15;
  const int quad = lane >> 4;
  const int wm = wave >> 2;  // 0..1
  const int wn = wave & 3;   // 0..3

  int lin = blockIdx.y * gridDim.x + blockIdx.x;
  const int nwg = gridDim.x * gridDim.y;
  if ((nwg & 7) == 0) lin = (lin & 7) * (nwg >> 3) + (lin >> 3);
  const int tn = (lin % gridDim.x) * 256;
  const int tm = (lin / gridDim.x) * 256;

  f32x4 acc[8][4];
#pragma unroll
  for (int i = 0; i < 8; ++i)
#pragma unroll
    for (int j = 0; j < 4; ++j) acc[i][j] = (f32x4){0.f, 0.f, 0.f, 0.f};

  const int r_st = tid >> 2;
  const int csrc = ((tid & 3) ^ ((tid >> 3) & 3)) * 8;
  const int wofs = wave * 512;

  const int rowA = wm * 16 + l15;
  const int rowB = wn * 16 + l15;
  const int cfr = (quad ^ ((l15 >> 1) & 3)) * 8;

  const int NT = K >> 5;

#define STAGE_HALF(G, ldg, grow0, kk, base)                                  \
  async_ld16((G) + (size_t)((grow0) + r_st) * (ldg) + (kk) + csrc,           \
             &smem[(base) + wofs])

#define STAGE4(kk, base)                                \
  do {                                                  \
    STAGE_HALF(A, lda, tm, (kk), (base));               \
    STAGE_HALF(Bt, K, tn, (kk), (base) + 8192);         \
    STAGE_HALF(Bt, K, tn + 128, (kk), (base) + 12288);  \
    STAGE_HALF(A, lda, tm + 128, (kk), (base) + 4096);  \
  } while (0)

  STAGE4(0, 0);
  STAGE4(32, 16384);
  asm volatile("s_waitcnt vmcnt(4)" ::: "memory");
  __builtin_amdgcn_s_barrier();

  int rb = 0;
  for (int t = 0; t < NT; ++t) {
    const int kst = (t + 2) << 5;
    const bool pf = (kst < K);
    const int sb = (rb >= 16384) ? rb - 16384 : rb + 32768;
    if (pf) STAGE4(kst, sb);

    bf16x8 a_[8], b_[4];
#pragma unroll
    for (int mh = 0; mh < 2; ++mh)
#pragma unroll
      for (int q = 0; q < 4; ++q)
        a_[mh * 4 + q] = *(const bf16x8*)&smem[rb + mh * 4096 +
                                               ((q * 32 + rowA) << 5) + cfr];
#pragma unroll
    for (int nh = 0; nh < 2; ++nh)
#pragma unroll
      for (int jn = 0; jn < 2; ++jn)
        b_[nh * 2 + jn] = *(const bf16x8*)&smem[rb + 8192 + nh * 4096 +
                                                ((jn * 64 + rowB) << 5) + cfr];

    __builtin_amdgcn_s_setprio(1);
#pragma unroll
    for (int f = 0; f < 8; ++f)
#pragma unroll
      for (int n = 0; n < 4; ++n) acc[f][n] = MFMA_16x16x32(a_[f], b_[n], acc[f][n]);
    __builtin_amdgcn_s_setprio(0);

    asm volatile("s_waitcnt vmcnt(4)" ::: "memory");
    if (!pf) asm volatile("s_waitcnt vmcnt(0)" ::: "memory");
    __builtin_amdgcn_s_barrier();
    rb = (rb == 32768) ? 0 : rb + 16384;
  }

  __syncthreads();

  const int isF32 = flag ? *flag : 0;
  if (isF32) {
#pragma unroll
    for (int f = 0; f < 8; ++f) {
      const int m0 = tm + (f >> 2) * 128 + (f & 3) * 32 + wm * 16 + quad * 4;
#pragma unroll
      for (int nidx = 0; nidx < 4; ++nidx) {
        const int col = tn + (nidx >> 1) * 128 + (nidx & 1) * 64 + wn * 16 + l15;
        float* cp = (float*)Cout + (size_t)m0 * N_out + col;
#pragma unroll
        for (int r = 0; r < 4; ++r) cp[(size_t)r * N_out] = acc[f][nidx][r];
      }
    }
  } else if (vT != nullptr && tn >= 2048) {
    // V-column blocks: store transposed directly from acc (4 consecutive rows
    // per lane = 8B contiguous in vT[col][pos]); skip qkv writes entirely.
#pragma unroll
    for (int f = 0; f < 8; ++f) {
      const int m0 = tm + (f >> 2) * 128 + (f & 3) * 32 + wm * 16;
      const int bb = m0 >> 12;
      const int pos = (m0 & 4095) + quad * 4;
#pragma unroll
      for (int nidx = 0; nidx < 4; ++nidx) {
        const int c = tn + (nidx >> 1) * 128 + ((nidx & 1) << 6) + wn * 16 + l15;
        us4 o;
        o[0] = __builtin_bit_cast(unsigned short, (bf16_t)acc[f][nidx][0]);
        o[1] = __builtin_bit_cast(unsigned short, (bf16_t)acc[f][nidx][1]);
        o[2] = __builtin_bit_cast(unsigned short, (bf16_t)acc[f][nidx][2]);
        o[3] = __builtin_bit_cast(unsigned short, (bf16_t)acc[f][nidx][3]);
        *(us4*)(vT + ((size_t)(bb * 1024 + c - 2048)) * 4096 + pos) = o;
      }
    }
  } else {
    bf16_t* stg = smem + wave * 1152;
#pragma unroll
    for (int f = 0; f < 8; ++f) {
#pragma unroll
      for (int nidx = 0; nidx < 4; ++nidx)
#pragma unroll
        for (int r = 0; r < 4; ++r)
          stg[(quad * 4 + r) * 72 + nidx * 16 + l15] = (bf16_t)acc[f][nidx][r];
      __asm__ volatile("s_waitcnt lgkmcnt(0)" ::: "memory");
      const int m0 = tm + (f >> 2) * 128 + (f & 3) * 32 + wm * 16;
#pragma unroll
      for (int p = 0; p < 2; ++p) {
        const int idx = lane + p * 64;
        const int row = idx >> 3, c8 = (idx & 7) * 8;
        uint4 u = *(const uint4*)(stg + row * 72 + c8);
        const int col = tn + ((c8 >> 5) << 7) + (((c8 >> 4) & 1) << 6) + wn * 16 + (c8 & 15);
        *(uint4*)((bf16_t*)Cout + (size_t)(m0 + row) * N_out + col) = u;
      }
      __asm__ volatile("s_waitcnt lgkmcnt(0)" ::: "memory");
    }
  }
#undef STAGE_HALF
#undef STAGE4
}

// ---------------------------------------------------------------------------
// Sliding-window attention. R2 version (best measured) — untouched.
// ---------------------------------------------------------------------------
__global__ __launch_bounds__(256) void attn_swa(bf16_t* qkv, const bf16_t* __restrict__ vT) {
  __shared__ alignas(16) bf16_t k_lds[64 * 72];   // [key][d]
  __shared__ alignas(16) bf16_t vt_lds[64 * 72];  // [d][key]
  __shared__ alignas(16) bf16_t p_lds[4 * 16 * 72];

  int wg = blockIdx.x;
  wg = (wg & 7) * 512 + (wg >> 3);
  const int b = wg >> 10;
  const int h = (wg >> 6) & 15;
  const int qt = wg & 63;
  const int blk = qt >> 2;
  const int wq = qt & 3;
  const int tid = threadIdx.x;
  const int wave = tid >> 6;
  const int lane = tid & 63;
  const int l15 = lane & 15;
  const int quad = lane >> 4;
  const int qw = qt * 64 + wave * 16;

  const size_t qoff = ((size_t)(b * 4096 + qw + l15)) * 3072 + h * 64;
  const bf16x8 qf0 = *(const bf16x8*)(qkv + qoff + quad * 8);
  const bf16x8 qf1 = *(const bf16x8*)(qkv + qoff + 32 + quad * 8);

  f32x4 of[4];
#pragma unroll
  for (int i = 0; i < 4; ++i) of[i] = (f32x4){0.f, 0.f, 0.f, 0.f};
  float m_i[4], l_i[4];
#pragma unroll
  for (int r = 0; r < 4; ++r) {
    m_i[r] = -1e30f;
    l_i[r] = 0.0f;
  }

  const int kb0 = blk * 256 - 256;
  const int kclo = (blk == 0) ? 4 : wq;
  const int kchi = wq + 4;

  const int row0 = tid >> 3;
  const int co8 = (tid & 7) * 8;
  const bf16_t* kbase = qkv + ((size_t)b * 4096) * 3072 + 1024 + h * 64;
  const bf16_t* vbase = vT + (((size_t)b * 16 + h) * 64) * 4096;
  uint4 kr0, kr1, vr0, vr1;

#define ISSUE_KV(KB)                                                           \
  do {                                                                         \
    kr0 = *(const uint4*)(kbase + (size_t)((KB) + row0) * 3072 + co8);         \
    kr1 = *(const uint4*)(kbase + (size_t)((KB) + row0 + 32) * 3072 + co8);    \
    vr0 = *(const uint4*)(vbase + (size_t)row0 * 4096 + (KB) + co8);           \
    vr1 = *(const uint4*)(vbase + (size_t)(row0 + 32) * 4096 + (KB) + co8);    \
  } while (0)

  ISSUE_KV(kb0 + kclo * 64);

  for (int kc = kclo; kc <= kchi; ++kc) {
    const int kb = kb0 + kc * 64;
    __syncthreads();
    *(uint4*)(k_lds + row0 * 72 + co8) = kr0;
    *(uint4*)(k_lds + (row0 + 32) * 72 + co8) = kr1;
    *(uint4*)(vt_lds + row0 * 72 + co8) = vr0;
    *(uint4*)(vt_lds + (row0 + 32) * 72 + co8) = vr1;
    if (kc < kchi) ISSUE_KV(kb + 64);
    __syncthreads();

    f32x4 s[4];
    __builtin_amdgcn_s_setprio(1);
#pragma unroll
    for (int nt = 0; nt < 4; ++nt) {
      bf16x8 kf0 = *(const bf16x8*)(k_lds + (nt * 16 + l15) * 72 + quad * 8);
      bf16x8 kf1 = *(const bf16x8*)(k_lds + (nt * 16 + l15) * 72 + 32 + quad * 8);
      f32x4 z = (f32x4){0.f, 0.f, 0.f, 0.f};
      z = MFMA_16x16x32(qf0, kf0, z);
      z = MFMA_16x16x32(qf1, kf1, z);
      s[nt] = z;
    }
    __builtin_amdgcn_s_setprio(0);

    float sv[4][4];
#pragma unroll
    for (int nt = 0; nt < 4; ++nt) {
      const int key = kb + nt * 16 + l15;
#pragma unroll
      for (int r = 0; r < 4; ++r) {
        const int p = qw + quad * 4 + r;
        const bool valid = (key <= p) && (key + 256 > p);
        sv[nt][r] = valid ? s[nt][r] * 0.125f : -1e30f;
      }
    }
    float rm[4];
#pragma unroll
    for (int r = 0; r < 4; ++r)
      rm[r] = fmaxf(fmaxf(sv[0][r], sv[1][r]), fmaxf(sv[2][r], sv[3][r]));
#pragma unroll
    for (int off = 1; off < 16; off <<= 1)
#pragma unroll
      for (int r = 0; r < 4; ++r) rm[r] = fmaxf(rm[r], __shfl_xor(rm[r], off));

    float mn[4], alpha[4];
#pragma unroll
    for (int r = 0; r < 4; ++r) {
      mn[r] = fmaxf(m_i[r], rm[r]);
      alpha[r] = __expf(m_i[r] - mn[r]);
      m_i[r] = mn[r];
    }

    float rs[4] = {0.f, 0.f, 0.f, 0.f};
#pragma unroll
    for (int nt = 0; nt < 4; ++nt)
#pragma unroll
      for (int r = 0; r < 4; ++r) {
        const float pv = (sv[nt][r] > -1e29f) ? __expf(sv[nt][r] - mn[r]) : 0.0f;
        rs[r] += pv;
        p_lds[wave * 1152 + (quad * 4 + r) * 72 + nt * 16 + l15] = (bf16_t)pv;
      }
#pragma unroll
    for (int off = 1; off < 16; off <<= 1)
#pragma unroll
      for (int r = 0; r < 4; ++r) rs[r] += __shfl_xor(rs[r], off);
#pragma unroll
    for (int r = 0; r < 4; ++r) l_i[r] = l_i[r] * alpha[r] + rs[r];
#pragma unroll
    for (int dt = 0; dt < 4; ++dt)
#pragma unroll
      for (int r = 0; r < 4; ++r) of[dt][r] *= alpha[r];

    __builtin_amdgcn_s_setprio(1);
#pragma unroll
    for (int kk = 0; kk < 2; ++kk) {
      bf16x8 pf = *(const bf16x8*)(p_lds + wave * 1152 + l15 * 72 + kk * 32 + quad * 8);
#pragma unroll
      for (int dt = 0; dt < 4; ++dt) {
        bf16x8 vf = *(const bf16x8*)(vt_lds + (dt * 16 + l15) * 72 + kk * 32 + quad * 8);
        of[dt] = MFMA_16x16x32(pf, vf, of[dt]);
      }
    }
    __builtin_amdgcn_s_setprio(0);
  }
#undef ISSUE_KV

  float inv[4];
#pragma unroll
  for (int r = 0; r < 4; ++r) inv[r] = 1.0f / fmaxf(l_i[r], 1e-20f);
  bf16_t* op = qkv + ((size_t)(b * 4096 + qw)) * 3072 + h * 64;  // overwrite Q cols
#pragma unroll
  for (int dt = 0; dt < 4; ++dt)
#pragma unroll
    for (int r = 0; r < 4; ++r)
      op[(size_t)(quad * 4 + r) * 3072 + dt * 16 + l15] = (bf16_t)(of[dt][r] * inv[r]);
}

// ---------------------------------------------------------------------------
extern "C" void kernel_launch(void* const* d_in, const int* in_sizes, int n_in,
                              void* d_out, int out_size, void* d_ws, size_t ws_size,
                              hipStream_t stream) {
  char* ws = (char*)d_ws;
  bf16_t* wTq = (bf16_t*)(ws);                    // [3072][1024]   6,291,456 B
  bf16_t* wTo = (bf16_t*)(ws + 6291456);          // [1024][1024]   2,097,152 B
  bf16_t* qkv = (bf16_t*)(ws + 8388608);          // [16384][3072] 100,663,296 B
  int* flag = (int*)(ws + 109051904);             // 4 B (total 109,051,908 B)

  bf16_t* xb = (bf16_t*)d_out;                    // converted x, [0, 32MB)
  bf16_t* vTb = (bf16_t*)((char*)d_out + 33554432);  // vT, [32MB, 64MB)
  // xb consumed by QKV GEMM (which writes vT into the other half of d_out);
  // vT consumed by attention; final GEMM overwrites all of d_out with f32.

  detect_dtype<<<1, 256, 0, stream>>>((const ushort_t*)d_in[0], flag);
  convert_to_bf16<<<1024, 256, 0, stream>>>(d_in[0], xb, 2097152, flag);
  transpose_cvt<<<dim3(48, 16), 256, 0, stream>>>(d_in[1], (ushort_t*)wTq, 1024, 3072,
                                                  flag);
  transpose_cvt<<<dim3(16, 16), 256, 0, stream>>>(d_in[2], (ushort_t*)wTo, 1024, 1024,
                                                  flag);
  // QKV GEMM with fused V-transpose (V cols -> vTb, Q/K cols -> qkv)
  gemm_bf16_t<0><<<dim3(12, 64), 512, 0, stream>>>(xb, 1024, wTq, qkv, 3072, 1024,
                                                   nullptr, vTb);
  attn_swa<<<dim3(4096), 256, 0, stream>>>(qkv, vTb);
  gemm_bf16_t<1><<<dim3(4, 64), 512, 0, stream>>>(qkv, 3072, wTo, d_out, 1024, 1024,
                                                  flag, nullptr);
}

// Round 9
// 356.741 us; speedup vs baseline: 1.0598x; 1.0051x over previous
//
#include <hip/hip_runtime.h>

typedef __bf16 bf16_t;
typedef __bf16 bf16x8 __attribute__((ext_vector_type(8)));
typedef float f32x4 __attribute__((ext_vector_type(4)));
typedef unsigned short ushort_t;

#define MFMA_16x16x32(a, b, c) __builtin_amdgcn_mfma_f32_16x16x32_bf16((a), (b), (c), 0, 0, 0)

// async global->LDS, 16B per lane. LDS dest must be wave-uniform; HW adds lane*16.
__device__ __forceinline__ void async_ld16(const void* gptr, void* lptr) {
  typedef __attribute__((address_space(1))) const unsigned int as1_t;
  typedef __attribute__((address_space(3))) unsigned int as3_t;
  __builtin_amdgcn_global_load_lds((as1_t*)(unsigned long long)gptr,
                                   (as3_t*)(unsigned int)(unsigned long long)lptr,
                                   16, 0, 0);
}

// ---------------------------------------------------------------------------
// Input-dtype detector (f32-read-as-bf16 has ~47% wild exponents in low halves).
// ---------------------------------------------------------------------------
__global__ void detect_dtype(const ushort_t* __restrict__ x, int* __restrict__ flag) {
  __shared__ int cnt[256];
  int c = 0;
#pragma unroll
  for (int i = 0; i < 16; ++i) {
    const ushort_t u = x[threadIdx.x * 16 + i];
    const int e = (u >> 7) & 0xFF;
    if ((u & 0x7FFF) != 0 && (e < 0x3A || e > 0xC0)) ++c;
  }
  cnt[threadIdx.x] = c;
  __syncthreads();
  if (threadIdx.x == 0) {
    int t = 0;
    for (int i = 0; i < 256; ++i) t += cnt[i];
    *flag = (t > 512) ? 1 : 0;
  }
}

// ---------------------------------------------------------------------------
// Normalize input to bf16 (flag==1: f32 src; else 16B copy). n8 = elems/8.
// ---------------------------------------------------------------------------
__global__ __launch_bounds__(256) void convert_to_bf16(const void* __restrict__ src,
                                                       bf16_t* __restrict__ dst, int n8,
                                                       const int* __restrict__ flag) {
  const int isF32 = *flag;
  int i = blockIdx.x * 256 + threadIdx.x;
  const int stride = gridDim.x * 256;
  if (isF32) {
    const float4* s = (const float4*)src;
    for (; i < n8; i += stride) {
      const float4 a = s[(size_t)i * 2];
      const float4 b = s[(size_t)i * 2 + 1];
      bf16x8 o;
      o[0] = (bf16_t)a.x; o[1] = (bf16_t)a.y; o[2] = (bf16_t)a.z; o[3] = (bf16_t)a.w;
      o[4] = (bf16_t)b.x; o[5] = (bf16_t)b.y; o[6] = (bf16_t)b.z; o[7] = (bf16_t)b.w;
      *(bf16x8*)(dst + (size_t)i * 8) = o;
    }
  } else {
    const uint4* s = (const uint4*)src;
    for (; i < n8; i += stride) ((uint4*)dst)[i] = s[i];
  }
}

// ---------------------------------------------------------------------------
// Fused convert + 64x64 transpose for weights: in (f32 or bf16 per flag)
// [R][C] -> out bf16 [C][R].
// ---------------------------------------------------------------------------
__global__ __launch_bounds__(256) void transpose_cvt(const void* __restrict__ in,
                                                     ushort_t* __restrict__ out,
                                                     int R, int C,
                                                     const int* __restrict__ flag) {
  __shared__ alignas(16) ushort_t t[64 * 72];
  const int tid = threadIdx.x;
  const int c0 = blockIdx.x * 64;
  const int r0 = blockIdx.y * 64;
  if (*flag) {
    const float* s = (const float*)in;
#pragma unroll
    for (int it = 0; it < 4; ++it) {
      int cid = tid + it * 256;            // 0..1023
      int row = cid >> 4, ch = (cid & 15) * 4;  // 4 f32 per chunk
      const float4 v = *(const float4*)(s + (size_t)(r0 + row) * C + c0 + ch);
      ushort_t* tp = t + row * 72 + ch;
      tp[0] = (ushort_t)__builtin_bit_cast(unsigned short, (bf16_t)v.x);
      tp[1] = (ushort_t)__builtin_bit_cast(unsigned short, (bf16_t)v.y);
      tp[2] = (ushort_t)__builtin_bit_cast(unsigned short, (bf16_t)v.z);
      tp[3] = (ushort_t)__builtin_bit_cast(unsigned short, (bf16_t)v.w);
    }
  } else {
    const ushort_t* s = (const ushort_t*)in;
#pragma unroll
    for (int it = 0; it < 2; ++it) {
      int cid = tid + it * 256;
      int row = cid >> 3, co = (cid & 7) * 8;
      *(uint4*)(t + row * 72 + co) = *(const uint4*)(s + (size_t)(r0 + row) * C + c0 + co);
    }
  }
  __syncthreads();
#pragma unroll
  for (int it = 0; it < 2; ++it) {
    int cid = tid + it * 256;
    int orow = cid >> 3, ko = (cid & 7) * 8;
    uint4 u;
    ushort_t* tp = (ushort_t*)&u;
#pragma unroll
    for (int j = 0; j < 8; ++j) tp[j] = t[(ko + j) * 72 + orow];
    *(uint4*)(out + (size_t)(c0 + orow) * R + r0 + ko) = u;
  }
}

// ---------------------------------------------------------------------------
// GEMM core: C[M][N] = A[M][K] * Bt[N][K]^T.  256x256 tile, BK=32, 8 waves,
// 512 threads, TRIPLE-buffered LDS, 1 barrier + counted vmcnt(4) per K-tile.
// V-FUSION (vT != nullptr, tn >= 2048): this block computes V columns.
// R8 epilogue: aggregate each nidx-group (64 cols x 256 pos, all 8 waves)
// through an LDS [64][264] tile, then store 64B-contiguous chunks per thread
// (8 threads = one col's full 512B run) -> kills R7's 32B-scatter write
// amplification (WRITE_SIZE 111 MB, +10 us on QKV).
// ---------------------------------------------------------------------------
__device__ __forceinline__ void gemm_core(const bf16_t* __restrict__ A, int lda,
                                          const bf16_t* __restrict__ Bt,
                                          void* __restrict__ Cout, int N_out, int K,
                                          const int* __restrict__ flag,
                                          bf16_t* __restrict__ vT) {
  __shared__ alignas(16) bf16_t smem[49152];  // 96 KiB: 3 x [A 8K | B 8K] elems
  const int tid = threadIdx.x;
  const int wave = tid >> 6;
  const int lane = tid & 63;
  const int l15 = lane & 15;
  const int quad = lane >> 4;
  const int wm = wave >> 2;  // 0..1
  const int wn = wave & 3;   // 0..3

  int lin = blockIdx.y * gridDim.x + blockIdx.x;
  const int nwg = gridDim.x * gridDim.y;
  if ((nwg & 7) == 0) lin = (lin & 7) * (nwg >> 3) + (lin >> 3);
  const int tn = (lin % gridDim.x) * 256;
  const int tm = (lin / gridDim.x) * 256;

  f32x4 acc[8][4];
#pragma unroll
  for (int i = 0; i < 8; ++i)
#pragma unroll
    for (int j = 0; j < 4; ++j) acc[i][j] = (f32x4){0.f, 0.f, 0.f, 0.f};

  const int r_st = tid >> 2;
  const int csrc = ((tid & 3) ^ ((tid >> 3) & 3)) * 8;
  const int wofs = wave * 512;

  const int rowA = wm * 16 + l15;
  const int rowB = wn * 16 + l15;
  const int cfr = (quad ^ ((l15 >> 1) & 3)) * 8;

  const int NT = K >> 5;

#define STAGE_HALF(G, ldg, grow0, kk, base)                                  \
  async_ld16((G) + (size_t)((grow0) + r_st) * (ldg) + (kk) + csrc,           \
             &smem[(base) + wofs])

#define STAGE4(kk, base)                                \
  do {                                                  \
    STAGE_HALF(A, lda, tm, (kk), (base));               \
    STAGE_HALF(Bt, K, tn, (kk), (base) + 8192);         \
    STAGE_HALF(Bt, K, tn + 128, (kk), (base) + 12288);  \
    STAGE_HALF(A, lda, tm + 128, (kk), (base) + 4096);  \
  } while (0)

  STAGE4(0, 0);
  STAGE4(32, 16384);
  asm volatile("s_waitcnt vmcnt(4)" ::: "memory");
  __builtin_amdgcn_s_barrier();

  int rb = 0;
  for (int t = 0; t < NT; ++t) {
    const int kst = (t + 2) << 5;
    const bool pf = (kst < K);
    const int sb = (rb >= 16384) ? rb - 16384 : rb + 32768;
    if (pf) STAGE4(kst, sb);

    bf16x8 a_[8], b_[4];
#pragma unroll
    for (int mh = 0; mh < 2; ++mh)
#pragma unroll
      for (int q = 0; q < 4; ++q)
        a_[mh * 4 + q] = *(const bf16x8*)&smem[rb + mh * 4096 +
                                               ((q * 32 + rowA) << 5) + cfr];
#pragma unroll
    for (int nh = 0; nh < 2; ++nh)
#pragma unroll
      for (int jn = 0; jn < 2; ++jn)
        b_[nh * 2 + jn] = *(const bf16x8*)&smem[rb + 8192 + nh * 4096 +
                                                ((jn * 64 + rowB) << 5) + cfr];

    __builtin_amdgcn_s_setprio(1);
#pragma unroll
    for (int f = 0; f < 8; ++f)
#pragma unroll
      for (int n = 0; n < 4; ++n) acc[f][n] = MFMA_16x16x32(a_[f], b_[n], acc[f][n]);
    __builtin_amdgcn_s_setprio(0);

    asm volatile("s_waitcnt vmcnt(4)" ::: "memory");
    if (!pf) asm volatile("s_waitcnt vmcnt(0)" ::: "memory");
    __builtin_amdgcn_s_barrier();
    rb = (rb == 32768) ? 0 : rb + 16384;
  }

  __syncthreads();

  const int isF32 = flag ? *flag : 0;
  if (isF32) {
#pragma unroll
    for (int f = 0; f < 8; ++f) {
      const int m0 = tm + (f >> 2) * 128 + (f & 3) * 32 + wm * 16 + quad * 4;
#pragma unroll
      for (int nidx = 0; nidx < 4; ++nidx) {
        const int col = tn + (nidx >> 1) * 128 + (nidx & 1) * 64 + wn * 16 + l15;
        float* cp = (float*)Cout + (size_t)m0 * N_out + col;
#pragma unroll
        for (int r = 0; r < 4; ++r) cp[(size_t)r * N_out] = acc[f][nidx][r];
      }
    }
  } else if (vT != nullptr && tn >= 2048) {
    // V blocks: aggregate per nidx-group through LDS [64][264], store 64B
    // contiguous per thread into vT[col][pos] (8 threads = 512B run per col).
    const int bb = tm >> 12;
    const int pbase = tm & 4095;
    bf16_t* stg = smem;  // 64*264*2B = 33.8 KB
#pragma unroll
    for (int g = 0; g < 4; ++g) {
      __syncthreads();  // previous group's reads done (g=0: redundant)
      const int colp = wn * 16 + l15;
#pragma unroll
      for (int f = 0; f < 8; ++f) {
        const int posl = (f >> 2) * 128 + (f & 3) * 32 + wm * 16 + quad * 4;
#pragma unroll
        for (int r = 0; r < 4; ++r)
          stg[colp * 264 + posl + r] = (bf16_t)acc[f][g][r];
      }
      __syncthreads();
      const int colr = tid >> 3;
      const int p0 = (tid & 7) * 32;
      const int cg = tn - 2048 + (g >> 1) * 128 + ((g & 1) << 6) + colr;
      bf16_t* dst = vT + ((size_t)(bb * 1024 + cg)) * 4096 + pbase + p0;
      const bf16_t* srcp = stg + colr * 264 + p0;
#pragma unroll
      for (int k = 0; k < 4; ++k)
        *(uint4*)(dst + k * 8) = *(const uint4*)(srcp + k * 8);
    }
  } else {
    bf16_t* stg = smem + wave * 1152;
#pragma unroll
    for (int f = 0; f < 8; ++f) {
#pragma unroll
      for (int nidx = 0; nidx < 4; ++nidx)
#pragma unroll
        for (int r = 0; r < 4; ++r)
          stg[(quad * 4 + r) * 72 + nidx * 16 + l15] = (bf16_t)acc[f][nidx][r];
      __asm__ volatile("s_waitcnt lgkmcnt(0)" ::: "memory");
      const int m0 = tm + (f >> 2) * 128 + (f & 3) * 32 + wm * 16;
#pragma unroll
      for (int p = 0; p < 2; ++p) {
        const int idx = lane + p * 64;
        const int row = idx >> 3, c8 = (idx & 7) * 8;
        uint4 u = *(const uint4*)(stg + row * 72 + c8);
        const int col = tn + ((c8 >> 5) << 7) + (((c8 >> 4) & 1) << 6) + wn * 16 + (c8 & 15);
        *(uint4*)((bf16_t*)Cout + (size_t)(m0 + row) * N_out + col) = u;
      }
      __asm__ volatile("s_waitcnt lgkmcnt(0)" ::: "memory");
    }
  }
#undef STAGE_HALF
#undef STAGE4
}

// Distinct names so rocprof rows disambiguate (template tags truncate).
__global__ __launch_bounds__(512) void gemm_qkv(const bf16_t* __restrict__ A, int lda,
                                                const bf16_t* __restrict__ Bt,
                                                void* __restrict__ Cout, int N_out,
                                                int K, bf16_t* __restrict__ vT) {
  gemm_core(A, lda, Bt, Cout, N_out, K, nullptr, vT);
}
__global__ __launch_bounds__(512) void gemm_outp(const bf16_t* __restrict__ A, int lda,
                                                 const bf16_t* __restrict__ Bt,
                                                 void* __restrict__ Cout, int N_out,
                                                 int K, const int* __restrict__ flag) {
  gemm_core(A, lda, Bt, Cout, N_out, K, flag, nullptr);
}

// ---------------------------------------------------------------------------
// Sliding-window attention. R2 version (best measured) — untouched.
// ---------------------------------------------------------------------------
__global__ __launch_bounds__(256) void attn_swa(bf16_t* qkv, const bf16_t* __restrict__ vT) {
  __shared__ alignas(16) bf16_t k_lds[64 * 72];   // [key][d]
  __shared__ alignas(16) bf16_t vt_lds[64 * 72];  // [d][key]
  __shared__ alignas(16) bf16_t p_lds[4 * 16 * 72];

  int wg = blockIdx.x;
  wg = (wg & 7) * 512 + (wg >> 3);
  const int b = wg >> 10;
  const int h = (wg >> 6) & 15;
  const int qt = wg & 63;
  const int blk = qt >> 2;
  const int wq = qt & 3;
  const int tid = threadIdx.x;
  const int wave = tid >> 6;
  const int lane = tid & 63;
  const int l15 = lane & 15;
  const int quad = lane >> 4;
  const int qw = qt * 64 + wave * 16;

  const size_t qoff = ((size_t)(b * 4096 + qw + l15)) * 3072 + h * 64;
  const bf16x8 qf0 = *(const bf16x8*)(qkv + qoff + quad * 8);
  const bf16x8 qf1 = *(const bf16x8*)(qkv + qoff + 32 + quad * 8);

  f32x4 of[4];
#pragma unroll
  for (int i = 0; i < 4; ++i) of[i] = (f32x4){0.f, 0.f, 0.f, 0.f};
  float m_i[4], l_i[4];
#pragma unroll
  for (int r = 0; r < 4; ++r) {
    m_i[r] = -1e30f;
    l_i[r] = 0.0f;
  }

  const int kb0 = blk * 256 - 256;
  const int kclo = (blk == 0) ? 4 : wq;
  const int kchi = wq + 4;

  const int row0 = tid >> 3;
  const int co8 = (tid & 7) * 8;
  const bf16_t* kbase = qkv + ((size_t)b * 4096) * 3072 + 1024 + h * 64;
  const bf16_t* vbase = vT + (((size_t)b * 16 + h) * 64) * 4096;
  uint4 kr0, kr1, vr0, vr1;

#define ISSUE_KV(KB)                                                           \
  do {                                                                         \
    kr0 = *(const uint4*)(kbase + (size_t)((KB) + row0) * 3072 + co8);         \
    kr1 = *(const uint4*)(kbase + (size_t)((KB) + row0 + 32) * 3072 + co8);    \
    vr0 = *(const uint4*)(vbase + (size_t)row0 * 4096 + (KB) + co8);           \
    vr1 = *(const uint4*)(vbase + (size_t)(row0 + 32) * 4096 + (KB) + co8);    \
  } while (0)

  ISSUE_KV(kb0 + kclo * 64);

  for (int kc = kclo; kc <= kchi; ++kc) {
    const int kb = kb0 + kc * 64;
    __syncthreads();
    *(uint4*)(k_lds + row0 * 72 + co8) = kr0;
    *(uint4*)(k_lds + (row0 + 32) * 72 + co8) = kr1;
    *(uint4*)(vt_lds + row0 * 72 + co8) = vr0;
    *(uint4*)(vt_lds + (row0 + 32) * 72 + co8) = vr1;
    if (kc < kchi) ISSUE_KV(kb + 64);
    __syncthreads();

    f32x4 s[4];
    __builtin_amdgcn_s_setprio(1);
#pragma unroll
    for (int nt = 0; nt < 4; ++nt) {
      bf16x8 kf0 = *(const bf16x8*)(k_lds + (nt * 16 + l15) * 72 + quad * 8);
      bf16x8 kf1 = *(const bf16x8*)(k_lds + (nt * 16 + l15) * 72 + 32 + quad * 8);
      f32x4 z = (f32x4){0.f, 0.f, 0.f, 0.f};
      z = MFMA_16x16x32(qf0, kf0, z);
      z = MFMA_16x16x32(qf1, kf1, z);
      s[nt] = z;
    }
    __builtin_amdgcn_s_setprio(0);

    float sv[4][4];
#pragma unroll
    for (int nt = 0; nt < 4; ++nt) {
      const int key = kb + nt * 16 + l15;
#pragma unroll
      for (int r = 0; r < 4; ++r) {
        const int p = qw + quad * 4 + r;
        const bool valid = (key <= p) && (key + 256 > p);
        sv[nt][r] = valid ? s[nt][r] * 0.125f : -1e30f;
      }
    }
    float rm[4];
#pragma unroll
    for (int r = 0; r < 4; ++r)
      rm[r] = fmaxf(fmaxf(sv[0][r], sv[1][r]), fmaxf(sv[2][r], sv[3][r]));
#pragma unroll
    for (int off = 1; off < 16; off <<= 1)
#pragma unroll
      for (int r = 0; r < 4; ++r) rm[r] = fmaxf(rm[r], __shfl_xor(rm[r], off));

    float mn[4], alpha[4];
#pragma unroll
    for (int r = 0; r < 4; ++r) {
      mn[r] = fmaxf(m_i[r], rm[r]);
      alpha[r] = __expf(m_i[r] - mn[r]);
      m_i[r] = mn[r];
    }

    float rs[4] = {0.f, 0.f, 0.f, 0.f};
#pragma unroll
    for (int nt = 0; nt < 4; ++nt)
#pragma unroll
      for (int r = 0; r < 4; ++r) {
        const float pv = (sv[nt][r] > -1e29f) ? __expf(sv[nt][r] - mn[r]) : 0.0f;
        rs[r] += pv;
        p_lds[wave * 1152 + (quad * 4 + r) * 72 + nt * 16 + l15] = (bf16_t)pv;
      }
#pragma unroll
    for (int off = 1; off < 16; off <<= 1)
#pragma unroll
      for (int r = 0; r < 4; ++r) rs[r] += __shfl_xor(rs[r], off);
#pragma unroll
    for (int r = 0; r < 4; ++r) l_i[r] = l_i[r] * alpha[r] + rs[r];
#pragma unroll
    for (int dt = 0; dt < 4; ++dt)
#pragma unroll
      for (int r = 0; r < 4; ++r) of[dt][r] *= alpha[r];

    __builtin_amdgcn_s_setprio(1);
#pragma unroll
    for (int kk = 0; kk < 2; ++kk) {
      bf16x8 pf = *(const bf16x8*)(p_lds + wave * 1152 + l15 * 72 + kk * 32 + quad * 8);
#pragma unroll
      for (int dt = 0; dt < 4; ++dt) {
        bf16x8 vf = *(const bf16x8*)(vt_lds + (dt * 16 + l15) * 72 + kk * 32 + quad * 8);
        of[dt] = MFMA_16x16x32(pf, vf, of[dt]);
      }
    }
    __builtin_amdgcn_s_setprio(0);
  }
#undef ISSUE_KV

  float inv[4];
#pragma unroll
  for (int r = 0; r < 4; ++r) inv[r] = 1.0f / fmaxf(l_i[r], 1e-20f);
  bf16_t* op = qkv + ((size_t)(b * 4096 + qw)) * 3072 + h * 64;  // overwrite Q cols
#pragma unroll
  for (int dt = 0; dt < 4; ++dt)
#pragma unroll
    for (int r = 0; r < 4; ++r)
      op[(size_t)(quad * 4 + r) * 3072 + dt * 16 + l15] = (bf16_t)(of[dt][r] * inv[r]);
}

// ---------------------------------------------------------------------------
extern "C" void kernel_launch(void* const* d_in, const int* in_sizes, int n_in,
                              void* d_out, int out_size, void* d_ws, size_t ws_size,
                              hipStream_t stream) {
  char* ws = (char*)d_ws;
  bf16_t* wTq = (bf16_t*)(ws);                    // [3072][1024]   6,291,456 B
  bf16_t* wTo = (bf16_t*)(ws + 6291456);          // [1024][1024]   2,097,152 B
  bf16_t* qkv = (bf16_t*)(ws + 8388608);          // [16384][3072] 100,663,296 B
  int* flag = (int*)(ws + 109051904);             // 4 B (total 109,051,908 B)

  bf16_t* xb = (bf16_t*)d_out;                    // converted x, [0, 32MB)
  bf16_t* vTb = (bf16_t*)((char*)d_out + 33554432);  // vT, [32MB, 64MB)
  // xb consumed by QKV GEMM (which writes vT into the other half of d_out);
  // vT consumed by attention; final GEMM overwrites all of d_out with f32.

  detect_dtype<<<1, 256, 0, stream>>>((const ushort_t*)d_in[0], flag);
  convert_to_bf16<<<1024, 256, 0, stream>>>(d_in[0], xb, 2097152, flag);
  transpose_cvt<<<dim3(48, 16), 256, 0, stream>>>(d_in[1], (ushort_t*)wTq, 1024, 3072,
                                                  flag);
  transpose_cvt<<<dim3(16, 16), 256, 0, stream>>>(d_in[2], (ushort_t*)wTo, 1024, 1024,
                                                  flag);
  // QKV GEMM with fused V-transpose (V cols -> vTb, Q/K cols -> qkv)
  gemm_qkv<<<dim3(12, 64), 512, 0, stream>>>(xb, 1024, wTq, qkv, 3072, 1024, vTb);
  attn_swa<<<dim3(4096), 256, 0, stream>>>(qkv, vTb);
  gemm_outp<<<dim3(4, 64), 512, 0, stream>>>(qkv, 3072, wTo, d_out, 1024, 1024, flag);
}